// Round 20
// baseline (147.713 us; speedup 1.0000x reference)
//
#include <hip/hip_runtime.h>

#define N_ 2048

typedef __attribute__((ext_vector_type(8))) __bf16 bf16x8;
typedef __attribute__((ext_vector_type(8))) unsigned short u16x8;
typedef __attribute__((ext_vector_type(4))) float f32x4;

#define WAIT_VM(Nlit) asm volatile("s_waitcnt vmcnt(" #Nlit ")" ::: "memory")
#define WAIT_LGKM     asm volatile("s_waitcnt lgkmcnt(0)" ::: "memory")
#define SCHED_B       __builtin_amdgcn_sched_barrier(0)
#define S_BAR         __builtin_amdgcn_s_barrier()

__device__ inline unsigned short f2bf(float f) {
  return __builtin_bit_cast(unsigned short, static_cast<__bf16>(f));
}
__device__ inline float bf2f(unsigned short s) {
  unsigned u = ((unsigned)s) << 16;
  return __builtin_bit_cast(float, u);
}

__device__ inline f32x4 mfma_bf16(u16x8 a, u16x8 b, f32x4 c) {
  return __builtin_amdgcn_mfma_f32_16x16x32_bf16(
      __builtin_bit_cast(bf16x8, a), __builtin_bit_cast(bf16x8, b), c, 0, 0, 0);
}

// async global->LDS, 16B per lane: per-lane global src, LDS dest = uniform base + lane*16
__device__ __forceinline__ void gl_lds16(const void* g, void* l) {
  __builtin_amdgcn_global_load_lds(
      (const __attribute__((address_space(1))) unsigned int*)g,
      (__attribute__((address_space(3))) unsigned int*)l, 16, 0, 0);
}

// ---------------- prep: pack weights + X transpose (merged) ----------------
__global__ __launch_bounds__(256) void prep_all(
    const float* __restrict__ w0, const float* __restrict__ w1,
    const float* __restrict__ Wf, const float* __restrict__ X,
    unsigned short* __restrict__ Wc1, unsigned short* __restrict__ Wc2,
    unsigned short* __restrict__ Wcat, unsigned short* __restrict__ XbT,
    unsigned short* __restrict__ G)
{
  const int tid = threadIdx.x;
  int idx = blockIdx.x * 256 + tid;
  if (idx < 65536) {
    int h = idx >> 14, r = (idx >> 7) & 127, k = idx & 127;
    float v = (r < 64) ? w0[(h * 64 + r) * 128 + k]
                       : w1[(h * 64 + (r - 64)) * 192 + k];
    Wc1[idx] = f2bf(v);
  } else if (idx < 81920) {
    int i = idx - 65536;
    int h = i >> 12, r = (i >> 6) & 63, k = i & 63;
    Wc2[i] = f2bf(w1[(h * 64 + r) * 192 + 128 + k]);
  } else if (idx < 163840) {
    int i = idx - 81920;
    int d = i / 640, c = i % 640;
    float v;
    if (c < 256)      { int h = c >> 6, j = c & 63;        v = Wf[d * 512 + h * 128 + j]; }
    else if (c < 512) { int h = (c - 256) >> 6, j = (c - 256) & 63; v = Wf[d * 512 + h * 128 + 64 + j]; }
    else {
      int k = c - 512; v = 0.f;
      for (int hh = 0; hh < 4; ++hh) v += Wf[d * 512 + hh * 128 + k];
    }
    Wcat[i] = f2bf(v);
  }

  if (blockIdx.x < 128) {
    __shared__ float tf[64][129];
    const int b = blockIdx.x >> 5;
    const int n0 = (blockIdx.x & 31) * 64;
    #pragma unroll
    for (int i = 0; i < 32; ++i) {
      int e = i * 256 + tid;          // 64x128 tile
      int nl = e >> 7, c = e & 127;
      float v = X[((size_t)b * N_ + n0 + nl) * 128 + c];
      tf[nl][c] = v;
      G[((size_t)b * N_ + n0 + nl) * 640 + 512 + c] = f2bf(v);
    }
    __syncthreads();
    #pragma unroll
    for (int i = 0; i < 32; ++i) {
      int e = i * 256 + tid;
      int c = e >> 6, nl = e & 63;
      XbT[((size_t)b * 128 + c) * N_ + n0 + nl] = f2bf(tf[nl][c]);
    }
  }
}

// ---------------- pass1 (fused mid): 64 rows x 128 cols per block ----------------
// Phase A: Z0 = adj@X + X, denom; A-fragments emitted to adjT (tiled image).
// Stores stay in flight: writer waves (wc==0) wait vmcnt(12), others vmcnt(8).
// Phase B (in-block): g0 -> G, h0 -> h0T, e -> e_b.
__global__ __launch_bounds__(256, 2) void pass1_kernel(
    const float* __restrict__ adj, const float* __restrict__ X,
    const unsigned short* __restrict__ XbT,
    const unsigned short* __restrict__ Wc1, const unsigned short* __restrict__ Wc2,
    const float* __restrict__ bias0, const float* __restrict__ bias1,
    unsigned short* __restrict__ adjT, float* __restrict__ dnm,
    unsigned short* __restrict__ e_b, unsigned short* __restrict__ h0T,
    unsigned short* __restrict__ G)
{
  const int tid = threadIdx.x, lane = tid & 63, w = tid >> 6;
  const int wr = w >> 1, wc = w & 1;
  const int rl = lane & 15, q = lane >> 4;
  const int bh = blockIdx.y, b = bh >> 2, h = bh & 3, hb = h * 4 + b;
  const int row0 = blockIdx.x * 64;

  __shared__ __align__(16) char pool[65536];
  float* Af = (float*)pool;                              // [2][4096] = 2 x 16 KB
  unsigned short* Bt = (unsigned short*)(pool + 32768);  // [2][8192] = 2 x 16 KB

  const int r4 = lane >> 4, sA = lane & 15;
  const int r8 = lane >> 3, s8 = lane & 7;
  const int esB = (s8 ^ r8) * 8;
  const float* arow = adj + ((size_t)bh * N_ + row0) * N_;
  const unsigned short* xb = XbT + (size_t)b * 128 * N_;
  // tiled A output: [bh*32+blk][kb][wr][ks][rt][lane*8] u16 units
  unsigned short* atile = adjT + ((size_t)bh * 32 + blockIdx.x) * 131072;

  f32x4 acc[2][4] = {};
  float rs0 = 0.f, rs1 = 0.f;

  auto stage = [&](int buf, int kb) {
    #pragma unroll
    for (int j = 0; j < 4; ++j) {   // A fp32: rows w*16 + j*4 + r4
      const int R0 = w * 16 + j * 4;
      const int esA = (sA ^ ((j & 1) * 4 + r4)) * 4;
      gl_lds16(arow + (size_t)(R0 + r4) * N_ + kb * 64 + esA, Af + buf * 4096 + R0 * 64);
    }
    #pragma unroll
    for (int j = 0; j < 4; ++j) {   // B bf16: rows (w*4+j)*8 + r8
      const int R0 = (w * 4 + j) * 8;
      gl_lds16(xb + (size_t)(R0 + r8) * N_ + kb * 64 + esB, Bt + buf * 8192 + R0 * 64);
    }
  };
  auto compute = [&](int cur, int kb) {
    #pragma unroll
    for (int ks = 0; ks < 2; ++ks) {
      u16x8 aF[2];
      #pragma unroll
      for (int rt = 0; rt < 2; ++rt) {
        const int R = wr * 32 + rt * 16 + rl;
        const int m = R & 7;
        f32x4 f0 = *(const f32x4*)(Af + cur * 4096 + R * 64 + (ks * 8 + ((q * 2) ^ m)) * 4);
        f32x4 f1 = *(const f32x4*)(Af + cur * 4096 + R * 64 + (ks * 8 + ((q * 2 + 1) ^ m)) * 4);
        float sr = (f0.x + f0.y) + (f0.z + f0.w) + (f1.x + f1.y) + (f1.z + f1.w);
        if (rt == 0) rs0 += sr; else rs1 += sr;
        u16x8 v;
        v[0] = f2bf(f0.x); v[1] = f2bf(f0.y); v[2] = f2bf(f0.z); v[3] = f2bf(f0.w);
        v[4] = f2bf(f1.x); v[5] = f2bf(f1.y); v[6] = f2bf(f1.z); v[7] = f2bf(f1.w);
        aF[rt] = v;
      }
      if (wc == 0) {   // emit tiled bf16 A-fragments (writer waves: w=0,2)
        #pragma unroll
        for (int rt = 0; rt < 2; ++rt)
          *(u16x8*)(atile + (size_t)kb * 4096 + wr * 2048 + ks * 1024 + rt * 512 + lane * 8) = aF[rt];
      }
      #pragma unroll
      for (int ct = 0; ct < 4; ++ct) {
        const int C = wc * 64 + ct * 16 + rl;
        u16x8 bF = *(const u16x8*)((const char*)(Bt + cur * 8192) + C * 128 +
                                   (((ks * 4 + q) ^ (C & 7)) * 16));
        acc[0][ct] = mfma_bf16(aF[0], bF, acc[0][ct]);
        acc[1][ct] = mfma_bf16(aF[1], bF, acc[1][ct]);
      }
    }
  };

  stage(0, 0);
  int cur = 0;
  for (int kb = 0; kb < 31; ++kb) {
    stage(cur ^ 1, kb + 1);
    // retire stage(kb); writer waves keep 4 stores + stage(kb+1) in flight
    if (kb == 0 || wc != 0) { WAIT_VM(8); } else { WAIT_VM(12); }
    SCHED_B;
    S_BAR;       SCHED_B;
    compute(cur, kb);
    WAIT_LGKM;   SCHED_B;
    S_BAR;       SCHED_B;
    cur ^= 1;
  }
  WAIT_VM(0);  SCHED_B;
  S_BAR;       SCHED_B;
  compute(cur, 31);

  rs0 += __shfl_xor(rs0, 16, 64);
  rs0 += __shfl_xor(rs0, 32, 64);
  rs1 += __shfl_xor(rs1, 16, 64);
  rs1 += __shfl_xor(rs1, 32, 64);

  WAIT_VM(0); SCHED_B;      // drain A-fragment stores
  WAIT_LGKM;  SCHED_B;
  S_BAR;      SCHED_B;      // pool reusable

  // ---- phase B: pool reuse ----
  unsigned short (*Zs)[136] = (unsigned short (*)[136])pool;  // 64 x 136 bf16
  float* denL = (float*)(pool + 20480);
  unsigned short* g0s = (unsigned short*)(pool + 24576);       // [64][72]
  unsigned short* h0s = (unsigned short*)(pool + 36864);       // [64][72]

  if (q == 0 && wc == 0) {
    const int na = wr * 32 + rl, nb2 = wr * 32 + 16 + rl;
    denL[na]  = rs0 + 1.0f;
    denL[nb2] = rs1 + 1.0f;
    dnm[(size_t)hb * N_ + row0 + na]  = rs0 + 1.0f;
    dnm[(size_t)hb * N_ + row0 + nb2] = rs1 + 1.0f;
  }

  #pragma unroll
  for (int rt = 0; rt < 2; ++rt) {
    #pragma unroll
    for (int j = 0; j < 4; ++j) {
      const int r = wr * 32 + rt * 16 + q * 4 + j;
      const float* xr = X + ((size_t)b * N_ + row0 + r) * 128;
      #pragma unroll
      for (int ct = 0; ct < 4; ++ct) {
        const int c = wc * 64 + ct * 16 + rl;
        Zs[r][c] = f2bf(acc[rt][ct][j] + xr[c]);
      }
    }
  }
  __syncthreads();

  // GEMM1: t = Z @ Wc1^T
  f32x4 acc1[8] = {};
  #pragma unroll
  for (int ks = 0; ks < 4; ++ks) {
    u16x8 aF = *(const u16x8*)&Zs[w * 16 + rl][ks * 32 + q * 8];
    #pragma unroll
    for (int ct = 0; ct < 8; ++ct) {
      u16x8 bF = *(const u16x8*)(Wc1 + ((size_t)h * 128 + ct * 16 + rl) * 128 + ks * 32 + q * 8);
      acc1[ct] = mfma_bf16(aF, bF, acc1[ct]);
    }
  }

  #pragma unroll
  for (int j = 0; j < 4; ++j) {
    const int row = q * 4 + j;
    const float den = denL[w * 16 + row];
    const size_t gr = (size_t)b * N_ + row0 + w * 16 + row;
    #pragma unroll
    for (int ct = 0; ct < 4; ++ct) {
      const int c = ct * 16 + rl;
      float g = (acc1[ct][j] + 2.f * bias0[h * 64 + c]) / den;
      unsigned short gb = f2bf(fmaxf(g, 0.f));
      g0s[(w * 16 + row) * 72 + c] = gb;
      G[gr * 640 + h * 64 + c] = gb;
    }
  }
  __syncthreads();

  // GEMM2: h0 = g0 @ w1b^T
  f32x4 acc2[4] = {};
  #pragma unroll
  for (int ks = 0; ks < 2; ++ks) {
    u16x8 aF = *(const u16x8*)&g0s[(w * 16 + rl) * 72 + ks * 32 + q * 8];
    #pragma unroll
    for (int ct = 0; ct < 4; ++ct) {
      u16x8 bF = *(const u16x8*)(Wc2 + ((size_t)h * 64 + ct * 16 + rl) * 64 + ks * 32 + q * 8);
      acc2[ct] = mfma_bf16(aF, bF, acc2[ct]);
    }
  }

  #pragma unroll
  for (int j = 0; j < 4; ++j) {
    const int row = q * 4 + j;
    #pragma unroll
    for (int ct = 0; ct < 4; ++ct) {
      const int c = ct * 16 + rl;
      float h0v = acc2[ct][j];
      float ev = acc1[4 + ct][j] + h0v + 2.f * bias1[h * 64 + c];
      e_b[((size_t)h * 8192 + b * 2048 + row0 + w * 16 + row) * 64 + c] = f2bf(ev);
      h0s[(w * 16 + row) * 72 + c] = f2bf(h0v);
    }
  }
  __syncthreads();

  {
    u16x8 t0, t1;
    #pragma unroll
    for (int r = 0; r < 8; ++r) t0[r] = h0s[(w * 16 + r) * 72 + lane];
    #pragma unroll
    for (int r = 0; r < 8; ++r) t1[r] = h0s[(w * 16 + 8 + r) * 72 + lane];
    unsigned short* dst = h0T + (((size_t)h * 4 + b) * 64 + lane) * N_ + row0 + w * 16;
    *(u16x8*)dst = t0;
    *(u16x8*)(dst + 8) = t1;
  }
}

// ---------------- pass2: g1 = relu((adjT@h0 + e)/den) ----------------
// 64 rows x 64 cols per block. A from tiled image: 8KB contiguous per chunk,
// per-lane linear src, linear LDS, lane*16 reads. B (h0T) swizzled. Counted vmcnt.
__global__ __launch_bounds__(256, 2) void pass2_kernel(
    const unsigned short* __restrict__ adjT, const unsigned short* __restrict__ h0T,
    const unsigned short* __restrict__ e_b, const float* __restrict__ dnm,
    unsigned short* __restrict__ G)
{
  const int tid = threadIdx.x, lane = tid & 63, w = tid >> 6;
  const int wr = w >> 1, wc = w & 1;
  const int rl = lane & 15, q = lane >> 4;
  const int bh = blockIdx.y, b = bh >> 2, h = bh & 3, hb = h * 4 + b;

  __shared__ __align__(16) unsigned short Ab[2][4096];  // 2 x 8 KB, linear image
  __shared__ __align__(16) unsigned short Bt[2][4096];  // 2 x 8 KB

  const int r8 = lane >> 3, s8 = lane & 7;
  const int esB = (s8 ^ r8) * 8;
  const unsigned short* atile = adjT + ((size_t)bh * 32 + blockIdx.x) * 131072;
  const unsigned short* hbse = h0T + (size_t)hb * 64 * N_;
  const int row0 = blockIdx.x * 64;

  f32x4 acc[2][2] = {};

  auto stage = [&](int buf, int kb) {
    #pragma unroll
    for (int j = 0; j < 2; ++j) {   // A: contiguous 1KB per inst, per-lane linear src
      const int i = w * 2 + j;
      gl_lds16(atile + (size_t)kb * 4096 + i * 512 + lane * 8, &Ab[buf][i * 512]);
    }
    #pragma unroll
    for (int j = 0; j < 2; ++j) {   // B: rows (w*2+j)*8 + r8, swizzled src
      const int R0 = (w * 2 + j) * 8;
      gl_lds16(hbse + (size_t)(R0 + r8) * N_ + kb * 64 + esB, &Bt[buf][R0 * 64]);
    }
  };
  auto compute = [&](int cur) {
    #pragma unroll
    for (int ks = 0; ks < 2; ++ks) {
      u16x8 aF[2];
      #pragma unroll
      for (int rt = 0; rt < 2; ++rt)
        aF[rt] = *(const u16x8*)&Ab[cur][wr * 2048 + ks * 1024 + rt * 512 + lane * 8];
      #pragma unroll
      for (int ct = 0; ct < 2; ++ct) {
        const int C = wc * 32 + ct * 16 + rl;
        u16x8 bF = *(const u16x8*)&Bt[cur][C * 64 + (((ks * 4 + q) ^ (C & 7)) * 8)];
        acc[0][ct] = mfma_bf16(aF[0], bF, acc[0][ct]);
        acc[1][ct] = mfma_bf16(aF[1], bF, acc[1][ct]);
      }
    }
  };

  stage(0, 0);
  int cur = 0;
  for (int kb = 0; kb < 31; ++kb) {
    stage(cur ^ 1, kb + 1);
    WAIT_VM(4);  SCHED_B;
    S_BAR;       SCHED_B;
    compute(cur);
    WAIT_LGKM;   SCHED_B;
    S_BAR;       SCHED_B;
    cur ^= 1;
  }
  WAIT_VM(0);  SCHED_B;
  S_BAR;       SCHED_B;
  compute(cur);

  #pragma unroll
  for (int rt = 0; rt < 2; ++rt) {
    #pragma unroll
    for (int j = 0; j < 4; ++j) {
      const int n = row0 + wr * 32 + rt * 16 + q * 4 + j;
      const float den = dnm[(size_t)hb * N_ + n];
      const unsigned short* er = e_b + ((size_t)hb * N_ + n) * 64;
      unsigned short* gr = G + ((size_t)b * N_ + n) * 640 + 256 + h * 64;
      #pragma unroll
      for (int ct = 0; ct < 2; ++ct) {
        const int c = wc * 32 + ct * 16 + rl;
        float v = (acc[rt][ct][j] + bf2f(er[c])) / den;
        gr[c] = f2bf(fmaxf(v, 0.f));
      }
    }
  }
}

// ---------------- pass3: out = G @ Wcat^T + bf ----------------
__global__ __launch_bounds__(256) void pass3_kernel(
    const unsigned short* __restrict__ G, const unsigned short* __restrict__ Wcat,
    const float* __restrict__ bfv, float* __restrict__ out)
{
  const int tid = threadIdx.x, lane = tid & 63, w = tid >> 6;
  const int wc = w & 1, kc = w >> 1, rl = lane & 15, q = lane >> 4;
  const int row0 = blockIdx.x * 16;   // over B*N = 8192

  __shared__ float red[2][16][68];

  const unsigned short* aP = G + (size_t)(row0 + rl) * 640 + kc * 320 + q * 8;
  const unsigned short* wP = Wcat + (size_t)kc * 320 + q * 8;

  f32x4 acc[4] = {};
  #pragma unroll
  for (int t = 0; t < 10; ++t) {
    u16x8 aF = *(const u16x8*)(aP + (size_t)t * 32);
    #pragma unroll
    for (int ct = 0; ct < 4; ++ct) {
      u16x8 bF = *(const u16x8*)(wP + (size_t)(wc * 64 + ct * 16 + rl) * 640 + t * 32);
      acc[ct] = mfma_bf16(aF, bF, acc[ct]);
    }
  }

  if (kc == 1) {
    #pragma unroll
    for (int j = 0; j < 4; ++j)
      #pragma unroll
      for (int ct = 0; ct < 4; ++ct)
        red[wc][q * 4 + j][ct * 16 + rl] = acc[ct][j];
  }
  __syncthreads();
  if (kc == 0) {
    #pragma unroll
    for (int j = 0; j < 4; ++j) {
      const int row = q * 4 + j;
      float* orow = out + (size_t)(row0 + row) * 128;
      #pragma unroll
      for (int ct = 0; ct < 4; ++ct) {
        const int c = wc * 64 + ct * 16 + rl;
        orow[c] = acc[ct][j] + red[wc][row][ct * 16 + rl] + bfv[c];
      }
    }
  }
}

// ---------------- launch ----------------
extern "C" void kernel_launch(void* const* d_in, const int* in_sizes, int n_in,
                              void* d_out, int out_size, void* d_ws, size_t ws_size,
                              hipStream_t stream) {
  const float* adj = (const float*)d_in[0];
  const float* X   = (const float*)d_in[1];
  const float* w0  = (const float*)d_in[2];
  const float* b0  = (const float*)d_in[3];
  const float* w1  = (const float*)d_in[4];
  const float* b1  = (const float*)d_in[5];
  const float* Wf  = (const float*)d_in[6];
  const float* bf  = (const float*)d_in[7];
  float* out = (float*)d_out;
  char* ws = (char*)d_ws;

  unsigned short* XbT  = (unsigned short*)(ws + 0);          //  2,097,152
  unsigned short* Wc1  = (unsigned short*)(ws + 2097152);    //    131,072
  unsigned short* Wc2  = (unsigned short*)(ws + 2228224);    //     32,768
  unsigned short* Wcat = (unsigned short*)(ws + 2260992);    //    163,840
  float*          dnm  = (float*)(ws + 2424832);             //    131,072
  unsigned short* e_b  = (unsigned short*)(ws + 2555904);    //  4,194,304
  unsigned short* h0T  = (unsigned short*)(ws + 6750208);    //  4,194,304
  unsigned short* G    = (unsigned short*)(ws + 10944512);   // 10,485,760
  unsigned short* adjT = (unsigned short*)(ws + 33554432);   // 134,217,728

  hipLaunchKernelGGL(prep_all, dim3(640), dim3(256), 0, stream,
                     w0, w1, Wf, X, Wc1, Wc2, Wcat, XbT, G);
  hipLaunchKernelGGL(pass1_kernel, dim3(32, 16), dim3(256), 0, stream,
                     adj, X, XbT, Wc1, Wc2, b0, b1, adjT, dnm, e_b, h0T, G);
  hipLaunchKernelGGL(pass2_kernel, dim3(32, 16), dim3(256), 0, stream, adjT, h0T, e_b, dnm, G);
  hipLaunchKernelGGL(pass3_kernel, dim3(512), dim3(256), 0, stream, G, Wcat, bf, out);
}

// Round 21
// 129.599 us; speedup vs baseline: 1.1398x; 1.1398x over previous
//
#include <hip/hip_runtime.h>

#define N_ 2048

typedef __attribute__((ext_vector_type(8))) __bf16 bf16x8;
typedef __attribute__((ext_vector_type(8))) unsigned short u16x8;
typedef __attribute__((ext_vector_type(4))) float f32x4;
typedef long long i64;

#define WAIT_VM(Nlit) asm volatile("s_waitcnt vmcnt(" #Nlit ")" ::: "memory")
#define WAIT_LGKM     asm volatile("s_waitcnt lgkmcnt(0)" ::: "memory")
#define SCHED_B       __builtin_amdgcn_sched_barrier(0)
#define S_BAR         __builtin_amdgcn_s_barrier()

__device__ inline unsigned short f2bf(float f) {
  return __builtin_bit_cast(unsigned short, static_cast<__bf16>(f));
}
__device__ inline float bf2f(unsigned short s) {
  unsigned u = ((unsigned)s) << 16;
  return __builtin_bit_cast(float, u);
}

__device__ inline f32x4 mfma_bf16(u16x8 a, u16x8 b, f32x4 c) {
  return __builtin_amdgcn_mfma_f32_16x16x32_bf16(
      __builtin_bit_cast(bf16x8, a), __builtin_bit_cast(bf16x8, b), c, 0, 0, 0);
}
__device__ inline f32x4 mfma_fp8(i64 a, i64 b, f32x4 c) {
  return __builtin_amdgcn_mfma_f32_16x16x32_fp8_fp8(a, b, c, 0, 0, 0);
}

// async global->LDS, 16B per lane: per-lane global src, LDS dest = uniform base + lane*16
__device__ __forceinline__ void gl_lds16(const void* g, void* l) {
  __builtin_amdgcn_global_load_lds(
      (const __attribute__((address_space(1))) unsigned int*)g,
      (__attribute__((address_space(3))) unsigned int*)l, 16, 0, 0);
}

// ---------------- prep: pack weights + X transpose (merged) ----------------
__global__ __launch_bounds__(256) void prep_all(
    const float* __restrict__ w0, const float* __restrict__ w1,
    const float* __restrict__ Wf, const float* __restrict__ X,
    unsigned short* __restrict__ Wc1, unsigned short* __restrict__ Wc2,
    unsigned short* __restrict__ Wcat, unsigned short* __restrict__ XbT,
    unsigned short* __restrict__ G)
{
  const int tid = threadIdx.x;
  int idx = blockIdx.x * 256 + tid;
  if (idx < 65536) {
    int h = idx >> 14, r = (idx >> 7) & 127, k = idx & 127;
    float v = (r < 64) ? w0[(h * 64 + r) * 128 + k]
                       : w1[(h * 64 + (r - 64)) * 192 + k];
    Wc1[idx] = f2bf(v);
  } else if (idx < 81920) {
    int i = idx - 65536;
    int h = i >> 12, r = (i >> 6) & 63, k = i & 63;
    Wc2[i] = f2bf(w1[(h * 64 + r) * 192 + 128 + k]);
  } else if (idx < 163840) {
    int i = idx - 81920;
    int d = i / 640, c = i % 640;
    float v;
    if (c < 256)      { int h = c >> 6, j = c & 63;        v = Wf[d * 512 + h * 128 + j]; }
    else if (c < 512) { int h = (c - 256) >> 6, j = (c - 256) & 63; v = Wf[d * 512 + h * 128 + 64 + j]; }
    else {
      int k = c - 512; v = 0.f;
      for (int hh = 0; hh < 4; ++hh) v += Wf[d * 512 + hh * 128 + k];
    }
    Wcat[i] = f2bf(v);
  }

  if (blockIdx.x < 128) {
    __shared__ float tf[64][129];
    const int b = blockIdx.x >> 5;
    const int n0 = (blockIdx.x & 31) * 64;
    #pragma unroll
    for (int i = 0; i < 32; ++i) {
      int e = i * 256 + tid;          // 64x128 tile
      int nl = e >> 7, c = e & 127;
      float v = X[((size_t)b * N_ + n0 + nl) * 128 + c];
      tf[nl][c] = v;
      G[((size_t)b * N_ + n0 + nl) * 640 + 512 + c] = f2bf(v);
    }
    __syncthreads();
    #pragma unroll
    for (int i = 0; i < 32; ++i) {
      int e = i * 256 + tid;
      int c = e >> 6, nl = e & 63;
      XbT[((size_t)b * 128 + c) * N_ + n0 + nl] = f2bf(tf[nl][c]);
    }
  }
}

// ---------------- pass1 (fused mid): 64 rows x 128 cols per block ----------------
// Phase A: Z0 = adj@X + X, denom; fp8 A-fragments emitted to adjT (tiled image).
// Stores stay in flight: writer waves (wc==0) wait vmcnt(12), others vmcnt(8).
// Phase B (in-block): g0 -> G (bf16), h0 -> h0T (fp8), e -> e_b (bf16).
__global__ __launch_bounds__(256, 2) void pass1_kernel(
    const float* __restrict__ adj, const float* __restrict__ X,
    const unsigned short* __restrict__ XbT,
    const unsigned short* __restrict__ Wc1, const unsigned short* __restrict__ Wc2,
    const float* __restrict__ bias0, const float* __restrict__ bias1,
    unsigned char* __restrict__ adjT8, float* __restrict__ dnm,
    unsigned short* __restrict__ e_b, unsigned char* __restrict__ h0T8,
    unsigned short* __restrict__ G)
{
  const int tid = threadIdx.x, lane = tid & 63, w = tid >> 6;
  const int wr = w >> 1, wc = w & 1;
  const int rl = lane & 15, q = lane >> 4;
  const int bh = blockIdx.y, b = bh >> 2, h = bh & 3, hb = h * 4 + b;
  const int row0 = blockIdx.x * 64;

  __shared__ __align__(16) char pool[65536];
  float* Af = (float*)pool;                              // [2][4096] = 2 x 16 KB
  unsigned short* Bt = (unsigned short*)(pool + 32768);  // [2][8192] = 2 x 16 KB

  const int r4 = lane >> 4, sA = lane & 15;
  const int r8 = lane >> 3, s8 = lane & 7;
  const int esB = (s8 ^ r8) * 8;
  const float* arow = adj + ((size_t)bh * N_ + row0) * N_;
  const unsigned short* xb = XbT + (size_t)b * 128 * N_;
  // tiled fp8 A output: [bh*32+blk][kb][wr][ks][rt][lane*8B]
  unsigned char* atile = adjT8 + ((size_t)bh * 32 + blockIdx.x) * 131072;

  f32x4 acc[2][4] = {};
  float rs0 = 0.f, rs1 = 0.f;

  auto stage = [&](int buf, int kb) {
    #pragma unroll
    for (int j = 0; j < 4; ++j) {   // A fp32: rows w*16 + j*4 + r4
      const int R0 = w * 16 + j * 4;
      const int esA = (sA ^ ((j & 1) * 4 + r4)) * 4;
      gl_lds16(arow + (size_t)(R0 + r4) * N_ + kb * 64 + esA, Af + buf * 4096 + R0 * 64);
    }
    #pragma unroll
    for (int j = 0; j < 4; ++j) {   // B bf16: rows (w*4+j)*8 + r8
      const int R0 = (w * 4 + j) * 8;
      gl_lds16(xb + (size_t)(R0 + r8) * N_ + kb * 64 + esB, Bt + buf * 8192 + R0 * 64);
    }
  };
  auto compute = [&](int cur, int kb) {
    #pragma unroll
    for (int ks = 0; ks < 2; ++ks) {
      u16x8 aF[2];
      #pragma unroll
      for (int rt = 0; rt < 2; ++rt) {
        const int R = wr * 32 + rt * 16 + rl;
        const int m = R & 7;
        f32x4 f0 = *(const f32x4*)(Af + cur * 4096 + R * 64 + (ks * 8 + ((q * 2) ^ m)) * 4);
        f32x4 f1 = *(const f32x4*)(Af + cur * 4096 + R * 64 + (ks * 8 + ((q * 2 + 1) ^ m)) * 4);
        float sr = (f0.x + f0.y) + (f0.z + f0.w) + (f1.x + f1.y) + (f1.z + f1.w);
        if (rt == 0) rs0 += sr; else rs1 += sr;
        if (wc == 0) {   // emit fp8 A-fragment (writer waves: w=0,2), 8 B
          unsigned d0 = __builtin_amdgcn_cvt_pk_fp8_f32(f0.x, f0.y, 0, 0);
          d0 = __builtin_amdgcn_cvt_pk_fp8_f32(f0.z, f0.w, d0, 1);
          unsigned d1 = __builtin_amdgcn_cvt_pk_fp8_f32(f1.x, f1.y, 0, 0);
          d1 = __builtin_amdgcn_cvt_pk_fp8_f32(f1.z, f1.w, d1, 1);
          *(uint2*)(atile + (size_t)kb * 4096 + wr * 2048 + ks * 1024 + rt * 512 + lane * 8) =
              make_uint2(d0, d1);
        }
        u16x8 v;
        v[0] = f2bf(f0.x); v[1] = f2bf(f0.y); v[2] = f2bf(f0.z); v[3] = f2bf(f0.w);
        v[4] = f2bf(f1.x); v[5] = f2bf(f1.y); v[6] = f2bf(f1.z); v[7] = f2bf(f1.w);
        aF[rt] = v;
      }
      #pragma unroll
      for (int ct = 0; ct < 4; ++ct) {
        const int C = wc * 64 + ct * 16 + rl;
        u16x8 bF = *(const u16x8*)((const char*)(Bt + cur * 8192) + C * 128 +
                                   (((ks * 4 + q) ^ (C & 7)) * 16));
        acc[0][ct] = mfma_bf16(aF[0], bF, acc[0][ct]);
        acc[1][ct] = mfma_bf16(aF[1], bF, acc[1][ct]);
      }
    }
  };

  stage(0, 0);
  int cur = 0;
  for (int kb = 0; kb < 31; ++kb) {
    stage(cur ^ 1, kb + 1);
    // retire stage(kb); writer waves keep 4 stores + stage(kb+1) in flight
    if (kb == 0 || wc != 0) { WAIT_VM(8); } else { WAIT_VM(12); }
    SCHED_B;
    S_BAR;       SCHED_B;
    compute(cur, kb);
    WAIT_LGKM;   SCHED_B;
    S_BAR;       SCHED_B;
    cur ^= 1;
  }
  WAIT_VM(0);  SCHED_B;
  S_BAR;       SCHED_B;
  compute(cur, 31);

  rs0 += __shfl_xor(rs0, 16, 64);
  rs0 += __shfl_xor(rs0, 32, 64);
  rs1 += __shfl_xor(rs1, 16, 64);
  rs1 += __shfl_xor(rs1, 32, 64);

  WAIT_VM(0); SCHED_B;      // drain A-fragment stores
  WAIT_LGKM;  SCHED_B;
  S_BAR;      SCHED_B;      // pool reusable

  // ---- phase B: pool reuse ----
  unsigned short (*Zs)[136] = (unsigned short (*)[136])pool;  // 64 x 136 bf16
  float* denL = (float*)(pool + 20480);
  unsigned short* g0s = (unsigned short*)(pool + 24576);       // [64][72]
  unsigned short* h0s = (unsigned short*)(pool + 36864);       // [64][72]

  if (q == 0 && wc == 0) {
    const int na = wr * 32 + rl, nb2 = wr * 32 + 16 + rl;
    denL[na]  = rs0 + 1.0f;
    denL[nb2] = rs1 + 1.0f;
    dnm[(size_t)hb * N_ + row0 + na]  = rs0 + 1.0f;
    dnm[(size_t)hb * N_ + row0 + nb2] = rs1 + 1.0f;
  }

  #pragma unroll
  for (int rt = 0; rt < 2; ++rt) {
    #pragma unroll
    for (int j = 0; j < 4; ++j) {
      const int r = wr * 32 + rt * 16 + q * 4 + j;
      const float* xr = X + ((size_t)b * N_ + row0 + r) * 128;
      #pragma unroll
      for (int ct = 0; ct < 4; ++ct) {
        const int c = wc * 64 + ct * 16 + rl;
        Zs[r][c] = f2bf(acc[rt][ct][j] + xr[c]);
      }
    }
  }
  __syncthreads();

  // GEMM1: t = Z @ Wc1^T
  f32x4 acc1[8] = {};
  #pragma unroll
  for (int ks = 0; ks < 4; ++ks) {
    u16x8 aF = *(const u16x8*)&Zs[w * 16 + rl][ks * 32 + q * 8];
    #pragma unroll
    for (int ct = 0; ct < 8; ++ct) {
      u16x8 bF = *(const u16x8*)(Wc1 + ((size_t)h * 128 + ct * 16 + rl) * 128 + ks * 32 + q * 8);
      acc1[ct] = mfma_bf16(aF, bF, acc1[ct]);
    }
  }

  #pragma unroll
  for (int j = 0; j < 4; ++j) {
    const int row = q * 4 + j;
    const float den = denL[w * 16 + row];
    const size_t gr = (size_t)b * N_ + row0 + w * 16 + row;
    #pragma unroll
    for (int ct = 0; ct < 4; ++ct) {
      const int c = ct * 16 + rl;
      float g = (acc1[ct][j] + 2.f * bias0[h * 64 + c]) / den;
      unsigned short gb = f2bf(fmaxf(g, 0.f));
      g0s[(w * 16 + row) * 72 + c] = gb;
      G[gr * 640 + h * 64 + c] = gb;
    }
  }
  __syncthreads();

  // GEMM2: h0 = g0 @ w1b^T
  f32x4 acc2[4] = {};
  #pragma unroll
  for (int ks = 0; ks < 2; ++ks) {
    u16x8 aF = *(const u16x8*)&g0s[(w * 16 + rl) * 72 + ks * 32 + q * 8];
    #pragma unroll
    for (int ct = 0; ct < 4; ++ct) {
      u16x8 bF = *(const u16x8*)(Wc2 + ((size_t)h * 64 + ct * 16 + rl) * 64 + ks * 32 + q * 8);
      acc2[ct] = mfma_bf16(aF, bF, acc2[ct]);
    }
  }

  #pragma unroll
  for (int j = 0; j < 4; ++j) {
    const int row = q * 4 + j;
    #pragma unroll
    for (int ct = 0; ct < 4; ++ct) {
      const int c = ct * 16 + rl;
      float h0v = acc2[ct][j];
      float ev = acc1[4 + ct][j] + h0v + 2.f * bias1[h * 64 + c];
      e_b[((size_t)h * 8192 + b * 2048 + row0 + w * 16 + row) * 64 + c] = f2bf(ev);
      h0s[(w * 16 + row) * 72 + c] = f2bf(h0v);
    }
  }
  __syncthreads();

  // transpose-write h0T as fp8: col = lane, 16 n-values packed into 16 B
  {
    unsigned d[4];
    #pragma unroll
    for (int g = 0; g < 4; ++g) {
      float v0 = bf2f(h0s[(w * 16 + 4 * g + 0) * 72 + lane]);
      float v1 = bf2f(h0s[(w * 16 + 4 * g + 1) * 72 + lane]);
      float v2 = bf2f(h0s[(w * 16 + 4 * g + 2) * 72 + lane]);
      float v3 = bf2f(h0s[(w * 16 + 4 * g + 3) * 72 + lane]);
      unsigned t = __builtin_amdgcn_cvt_pk_fp8_f32(v0, v1, 0, 0);
      d[g] = __builtin_amdgcn_cvt_pk_fp8_f32(v2, v3, t, 1);
    }
    unsigned char* dst = h0T8 + (((size_t)h * 4 + b) * 64 + lane) * N_ + row0 + w * 16;
    *(uint4*)dst = make_uint4(d[0], d[1], d[2], d[3]);
  }
}

// ---------------- pass2: g1 = relu((adjT@h0 + e)/den), all-fp8 MFMA ----------------
// 64 rows x 64 cols per block. A from fp8 tiled image (4KB/chunk, linear);
// B from fp8 h0T (4KB/chunk, 16B-granule XOR swizzle). Counted vmcnt(2).
__global__ __launch_bounds__(256, 2) void pass2_kernel(
    const unsigned char* __restrict__ adjT8, const unsigned char* __restrict__ h0T8,
    const unsigned short* __restrict__ e_b, const float* __restrict__ dnm,
    unsigned short* __restrict__ G)
{
  const int tid = threadIdx.x, lane = tid & 63, w = tid >> 6;
  const int wr = w >> 1, wc = w & 1;
  const int rl = lane & 15, q = lane >> 4;
  const int bh = blockIdx.y, b = bh >> 2, h = bh & 3, hb = h * 4 + b;

  __shared__ __align__(16) unsigned char Ab8[2][4096];  // 2 x 4 KB, linear image
  __shared__ __align__(16) unsigned char Bt8[2][4096];  // 2 x 4 KB

  const unsigned char* atile = adjT8 + ((size_t)bh * 32 + blockIdx.x) * 131072;
  const unsigned char* hbse = h0T8 + (size_t)hb * 64 * N_;
  const int row0 = blockIdx.x * 64;

  f32x4 acc[2][2] = {};

  auto stage = [&](int buf, int kb) {
    // A: 4KB image chunk, 1 inst/wave, per-lane linear src
    gl_lds16(atile + (size_t)kb * 4096 + w * 1024 + lane * 16, &Ab8[buf][w * 1024]);
    // B: 4KB (64 cols x 64 m fp8), 1 inst/wave, 16B-granule XOR pre-swizzled src
    gl_lds16(hbse + (size_t)(w * 16 + (lane >> 2)) * N_ + kb * 64 +
                 (((lane & 3) * 16) ^ (((lane >> 2) & 3) * 16)),
             &Bt8[buf][w * 1024]);
  };
  auto compute = [&](int cur) {
    #pragma unroll
    for (int ks = 0; ks < 2; ++ks) {
      i64 aF[2];
      #pragma unroll
      for (int rt = 0; rt < 2; ++rt)
        aF[rt] = *(const i64*)&Ab8[cur][wr * 2048 + ks * 1024 + rt * 512 + lane * 8];
      #pragma unroll
      for (int ct = 0; ct < 2; ++ct) {
        const int C = wc * 32 + ct * 16 + rl;
        i64 bF = *(const i64*)&Bt8[cur][C * 64 + ((ks * 32 + q * 8) ^ ((C & 3) * 16))];
        acc[0][ct] = mfma_fp8(aF[0], bF, acc[0][ct]);
        acc[1][ct] = mfma_fp8(aF[1], bF, acc[1][ct]);
      }
    }
  };

  stage(0, 0);
  int cur = 0;
  for (int kb = 0; kb < 31; ++kb) {
    stage(cur ^ 1, kb + 1);
    WAIT_VM(2);  SCHED_B;   // retire stage(kb); kb+1's 2 loads stay in flight
    S_BAR;       SCHED_B;
    compute(cur);
    WAIT_LGKM;   SCHED_B;
    S_BAR;       SCHED_B;
    cur ^= 1;
  }
  WAIT_VM(0);  SCHED_B;
  S_BAR;       SCHED_B;
  compute(cur);

  #pragma unroll
  for (int rt = 0; rt < 2; ++rt) {
    #pragma unroll
    for (int j = 0; j < 4; ++j) {
      const int n = row0 + wr * 32 + rt * 16 + q * 4 + j;
      const float den = dnm[(size_t)hb * N_ + n];
      const unsigned short* er = e_b + ((size_t)hb * N_ + n) * 64;
      unsigned short* gr = G + ((size_t)b * N_ + n) * 640 + 256 + h * 64;
      #pragma unroll
      for (int ct = 0; ct < 2; ++ct) {
        const int c = wc * 32 + ct * 16 + rl;
        float v = (acc[rt][ct][j] + bf2f(er[c])) / den;
        gr[c] = f2bf(fmaxf(v, 0.f));
      }
    }
  }
}

// ---------------- pass3: out = G @ Wcat^T + bf ----------------
__global__ __launch_bounds__(256) void pass3_kernel(
    const unsigned short* __restrict__ G, const unsigned short* __restrict__ Wcat,
    const float* __restrict__ bfv, float* __restrict__ out)
{
  const int tid = threadIdx.x, lane = tid & 63, w = tid >> 6;
  const int wc = w & 1, kc = w >> 1, rl = lane & 15, q = lane >> 4;
  const int row0 = blockIdx.x * 16;   // over B*N = 8192

  __shared__ float red[2][16][68];

  const unsigned short* aP = G + (size_t)(row0 + rl) * 640 + kc * 320 + q * 8;
  const unsigned short* wP = Wcat + (size_t)kc * 320 + q * 8;

  f32x4 acc[4] = {};
  #pragma unroll
  for (int t = 0; t < 10; ++t) {
    u16x8 aF = *(const u16x8*)(aP + (size_t)t * 32);
    #pragma unroll
    for (int ct = 0; ct < 4; ++ct) {
      u16x8 bF = *(const u16x8*)(wP + (size_t)(wc * 64 + ct * 16 + rl) * 640 + t * 32);
      acc[ct] = mfma_bf16(aF, bF, acc[ct]);
    }
  }

  if (kc == 1) {
    #pragma unroll
    for (int j = 0; j < 4; ++j)
      #pragma unroll
      for (int ct = 0; ct < 4; ++ct)
        red[wc][q * 4 + j][ct * 16 + rl] = acc[ct][j];
  }
  __syncthreads();
  if (kc == 0) {
    #pragma unroll
    for (int j = 0; j < 4; ++j) {
      const int row = q * 4 + j;
      float* orow = out + (size_t)(row0 + row) * 128;
      #pragma unroll
      for (int ct = 0; ct < 4; ++ct) {
        const int c = wc * 64 + ct * 16 + rl;
        orow[c] = acc[ct][j] + red[wc][row][ct * 16 + rl] + bfv[c];
      }
    }
  }
}

// ---------------- launch ----------------
extern "C" void kernel_launch(void* const* d_in, const int* in_sizes, int n_in,
                              void* d_out, int out_size, void* d_ws, size_t ws_size,
                              hipStream_t stream) {
  const float* adj = (const float*)d_in[0];
  const float* X   = (const float*)d_in[1];
  const float* w0  = (const float*)d_in[2];
  const float* b0  = (const float*)d_in[3];
  const float* w1  = (const float*)d_in[4];
  const float* b1  = (const float*)d_in[5];
  const float* Wf  = (const float*)d_in[6];
  const float* bf  = (const float*)d_in[7];
  float* out = (float*)d_out;
  char* ws = (char*)d_ws;

  unsigned short* XbT  = (unsigned short*)(ws + 0);          //  2,097,152
  unsigned short* Wc1  = (unsigned short*)(ws + 2097152);    //    131,072
  unsigned short* Wc2  = (unsigned short*)(ws + 2228224);    //     32,768
  unsigned short* Wcat = (unsigned short*)(ws + 2260992);    //    163,840
  float*          dnm  = (float*)(ws + 2424832);             //    131,072
  unsigned short* e_b  = (unsigned short*)(ws + 2555904);    //  4,194,304
  unsigned char*  h0T8 = (unsigned char*)(ws + 6750208);     //  2,097,152
  unsigned short* G    = (unsigned short*)(ws + 10944512);   // 10,485,760
  unsigned char*  adjT8 = (unsigned char*)(ws + 33554432);   // 67,108,864

  hipLaunchKernelGGL(prep_all, dim3(640), dim3(256), 0, stream,
                     w0, w1, Wf, X, Wc1, Wc2, Wcat, XbT, G);
  hipLaunchKernelGGL(pass1_kernel, dim3(32, 16), dim3(256), 0, stream,
                     adj, X, XbT, Wc1, Wc2, b0, b1, adjT8, dnm, e_b, h0T8, G);
  hipLaunchKernelGGL(pass2_kernel, dim3(32, 16), dim3(256), 0, stream, adjT8, h0T8, e_b, dnm, G);
  hipLaunchKernelGGL(pass3_kernel, dim3(512), dim3(256), 0, stream, G, Wcat, bf, out);
}